// Round 1
// baseline (2634.972 us; speedup 1.0000x reference)
//
#include <hip/hip_runtime.h>
#include <math.h>

typedef __bf16 bf16_t;
typedef __bf16 bf16x8 __attribute__((ext_vector_type(8)));
typedef float f32x4 __attribute__((ext_vector_type(4)));

// ---------------- f32 -> bf16 convert ----------------
__global__ void k_f2b(const float* __restrict__ in, bf16_t* __restrict__ out, int n8) {
    int idx = blockIdx.x * 256 + threadIdx.x;
    if (idx >= n8) return;
    const float* p = in + (size_t)idx * 8;
    bf16x8 r;
#pragma unroll
    for (int j = 0; j < 8; j++) r[j] = (bf16_t)p[j];
    *(bf16x8*)(out + (size_t)idx * 8) = r;
}

// ---------------- sinusoidal time embedding ----------------
__global__ void k_time_embed(const float* __restrict__ time, float* __restrict__ temb0) {
    int b = blockIdx.x;
    int j = threadIdx.x;              // 0..255
    float f = __expf((float)j * -0.036118981458730134f); // -ln(10000)/255
    float e = time[b] * f;
    temb0[(size_t)b * 512 + j] = sinf(e);
    temb0[(size_t)b * 512 + 256 + j] = cosf(e);
}

// ---------------- LayerNorm (or plain cast) -> bf16, rows of 512 ----------------
template<bool DO_NORM>
__global__ void k_ln(const float* __restrict__ x, const float* __restrict__ g,
                     const float* __restrict__ b, bf16_t* __restrict__ out) {
    int row = blockIdx.x * 4 + (threadIdx.x >> 6);
    int lane = threadIdx.x & 63;
    const float* xr = x + (size_t)row * 512 + lane * 8;
    float4 v0 = *(const float4*)xr;
    float4 v1 = *(const float4*)(xr + 4);
    float vals[8] = {v0.x, v0.y, v0.z, v0.w, v1.x, v1.y, v1.z, v1.w};
    bf16x8 r;
    if (DO_NORM) {
        float s = 0.f, sq = 0.f;
#pragma unroll
        for (int j = 0; j < 8; j++) { s += vals[j]; sq += vals[j] * vals[j]; }
#pragma unroll
        for (int m = 1; m < 64; m <<= 1) { s += __shfl_xor(s, m, 64); sq += __shfl_xor(sq, m, 64); }
        float mean = s * (1.0f / 512.0f);
        float var = sq * (1.0f / 512.0f) - mean * mean;
        float rstd = rsqrtf(var + 1e-5f);
        float4 g0 = *(const float4*)(g + lane * 8);
        float4 g1 = *(const float4*)(g + lane * 8 + 4);
        float4 b0 = *(const float4*)(b + lane * 8);
        float4 b1 = *(const float4*)(b + lane * 8 + 4);
        float gs[8] = {g0.x, g0.y, g0.z, g0.w, g1.x, g1.y, g1.z, g1.w};
        float bs[8] = {b0.x, b0.y, b0.z, b0.w, b1.x, b1.y, b1.z, b1.w};
#pragma unroll
        for (int j = 0; j < 8; j++) r[j] = (bf16_t)((vals[j] - mean) * rstd * gs[j] + bs[j]);
    } else {
#pragma unroll
        for (int j = 0; j < 8; j++) r[j] = (bf16_t)vals[j];
    }
    *(bf16x8*)(out + (size_t)row * 512 + lane * 8) = r;
}

// ---------------- head prep: LN(x[:, -1]) -> relu -> f32 z[32,512] ----------------
__global__ void k_head_prep(const float* __restrict__ x, const float* __restrict__ g,
                            const float* __restrict__ b, float* __restrict__ z) {
    int row = blockIdx.x * 4 + (threadIdx.x >> 6); // 0..31
    int lane = threadIdx.x & 63;
    const float* xr = x + ((size_t)row * 512 + 511) * 512 + lane * 8;
    float4 v0 = *(const float4*)xr;
    float4 v1 = *(const float4*)(xr + 4);
    float vals[8] = {v0.x, v0.y, v0.z, v0.w, v1.x, v1.y, v1.z, v1.w};
    float s = 0.f, sq = 0.f;
#pragma unroll
    for (int j = 0; j < 8; j++) { s += vals[j]; sq += vals[j] * vals[j]; }
#pragma unroll
    for (int m = 1; m < 64; m <<= 1) { s += __shfl_xor(s, m, 64); sq += __shfl_xor(sq, m, 64); }
    float mean = s * (1.0f / 512.0f);
    float var = sq * (1.0f / 512.0f) - mean * mean;
    float rstd = rsqrtf(var + 1e-5f);
    float o[8];
#pragma unroll
    for (int j = 0; j < 8; j++) {
        float gv = g[lane * 8 + j], bv = b[lane * 8 + j];
        o[j] = fmaxf((vals[j] - mean) * rstd * gv + bv, 0.0f);
    }
    float* zr = z + (size_t)row * 512 + lane * 8;
    *(float4*)zr = make_float4(o[0], o[1], o[2], o[3]);
    *(float4*)(zr + 4) = make_float4(o[4], o[5], o[6], o[7]);
}

// ---------------- small fp32 GEMM: C[32,N] = act(A[32,K] @ W[N,K]^T + bias) ----------------
template<int ACT>  // 0 none, 1 gelu(exact), 2 silu
__global__ __launch_bounds__(256)
void k_gemm32(const float* __restrict__ A, const float* __restrict__ W,
              const float* __restrict__ bias, float* __restrict__ out,
              int N, int K) {
    __shared__ float Asm[32 * 516];
    int tid = threadIdx.x;
    int n0 = blockIdx.x * 32;
    int nl = tid >> 3;   // 0..31
    int bq = tid & 7;    // b = bq + 8j
    float acc[4] = {0.f, 0.f, 0.f, 0.f};
    for (int k0 = 0; k0 < K; k0 += 512) {
        __syncthreads();
#pragma unroll
        for (int i = 0; i < 16; i++) {
            int fi = tid + i * 256;      // float4 id in [0,4096)
            int row = fi >> 7;
            int cc = (fi & 127) << 2;
            *(float4*)&Asm[row * 516 + cc] = *(const float4*)&A[(size_t)row * K + k0 + cc];
        }
        __syncthreads();
        const float* Wr = W + (size_t)(n0 + nl) * K + k0;
        for (int kk = 0; kk < 512; kk += 4) {
            float4 w4 = *(const float4*)(Wr + kk);
#pragma unroll
            for (int j = 0; j < 4; j++) {
                float4 a4 = *(const float4*)&Asm[(bq + j * 8) * 516 + kk];
                acc[j] += a4.x * w4.x + a4.y * w4.y + a4.z * w4.z + a4.w * w4.w;
            }
        }
    }
#pragma unroll
    for (int j = 0; j < 4; j++) {
        float v = acc[j] + bias[n0 + nl];
        if (ACT == 1) v = 0.5f * v * (1.0f + erff(v * 0.70710678118654752f));
        if (ACT == 2) v = v / (1.0f + __expf(-v));
        out[(size_t)(bq + j * 8) * N + n0 + nl] = v;
    }
}

// ---------------- MFMA GEMM: C[M,N] = A[M,K](bf16) @ W[N,K]^T(bf16) + bias, fused epilogues -------
enum { EPI_QKV = 0, EPI_RESID = 1, EPI_FILM = 2 };

template<int EPI>
__global__ __launch_bounds__(256, 2)
void k_gemm_bt(const bf16_t* __restrict__ A, const bf16_t* __restrict__ W,
               const float* __restrict__ bias, void* __restrict__ outp,
               const float* __restrict__ tm, int l_off,
               int M, int N, int K) {
    __shared__ bf16_t Abuf[128 * 64];
    __shared__ bf16_t Bbuf[128 * 64];
    const int tid = threadIdx.x;
    const int m0 = blockIdx.x * 128;
    const int n0 = blockIdx.y * 128;
    const int lane = tid & 63;
    const int wave = tid >> 6;
    const int wr = (wave >> 1) * 64;
    const int wc = (wave & 1) * 64;
    const int srow = tid >> 1;
    const int scol = (tid & 1) * 32;       // elements
    const bf16_t* Arow = A + (size_t)(m0 + srow) * K + scol;
    const bf16_t* Wrow = W + (size_t)(n0 + srow) * K + scol;
    char* Ab = (char*)Abuf + srow * 128;
    char* Bb = (char*)Bbuf + srow * 128;
    const int swz = (srow & 7) << 4;
    f32x4 acc[4][4] = {};
    for (int k0 = 0; k0 < K; k0 += 64) {
        uint4 av[4], wv[4];
#pragma unroll
        for (int j = 0; j < 4; j++) {
            av[j] = *(const uint4*)(Arow + k0 + j * 8);
            wv[j] = *(const uint4*)(Wrow + k0 + j * 8);
        }
        __syncthreads();
#pragma unroll
        for (int j = 0; j < 4; j++) {
            int byt = (scol * 2 + j * 16) ^ swz;
            *(uint4*)(Ab + byt) = av[j];
            *(uint4*)(Bb + byt) = wv[j];
        }
        __syncthreads();
#pragma unroll
        for (int kk = 0; kk < 2; kk++) {
            bf16x8 af[4], bfr[4];
#pragma unroll
            for (int i = 0; i < 4; i++) {
                int ar = wr + i * 16 + (lane & 15);
                af[i] = *(const bf16x8*)((const char*)Abuf + ar * 128 +
                         ((kk * 64 + (lane >> 4) * 16) ^ ((ar & 7) << 4)));
                int br = wc + i * 16 + (lane & 15);
                bfr[i] = *(const bf16x8*)((const char*)Bbuf + br * 128 +
                         ((kk * 64 + (lane >> 4) * 16) ^ ((br & 7) << 4)));
            }
#pragma unroll
            for (int i = 0; i < 4; i++)
#pragma unroll
                for (int j = 0; j < 4; j++)
                    acc[i][j] = __builtin_amdgcn_mfma_f32_16x16x32_bf16(af[i], bfr[j], acc[i][j], 0, 0, 0);
        }
    }
    // epilogue
#pragma unroll
    for (int i = 0; i < 4; i++) {
#pragma unroll
        for (int r = 0; r < 4; r++) {
            int row = m0 + wr + i * 16 + (lane >> 4) * 4 + r;
#pragma unroll
            for (int j = 0; j < 4; j++) {
                int col = n0 + wc + j * 16 + (lane & 15);
                float v = acc[i][j][r] + bias[col];
                if (EPI == EPI_QKV) {
                    int b = row >> 9, s = row & 511, h = col >> 6, dh = col & 63;
                    ((bf16_t*)outp)[(((size_t)b * 8 + h) * 512 + s) * 64 + dh] = (bf16_t)v;
                } else if (EPI == EPI_RESID) {
                    ((float*)outp)[(size_t)row * N + col] += v;
                } else { // EPI_FILM
                    int b = row >> 9;
                    float sc = tm[(size_t)b * 16384 + l_off + col];
                    float sh = tm[(size_t)b * 16384 + l_off + 2048 + col];
                    ((bf16_t*)outp)[(size_t)row * N + col] = (bf16_t)(v * (1.0f + sc) + sh);
                }
            }
        }
    }
}

// ---------------- ReGLU: act[m,j] = h1[m,j] * relu(h1[m,1024+j]) ----------------
__global__ void k_reglu(const bf16_t* __restrict__ h1, bf16_t* __restrict__ act) {
    size_t i = ((size_t)blockIdx.x * 256 + threadIdx.x) * 8; // over 16384*1024
    size_t m = i >> 10;
    size_t j = i & 1023;
    bf16x8 a = *(const bf16x8*)&h1[m * 2048 + j];
    bf16x8 g = *(const bf16x8*)&h1[m * 2048 + 1024 + j];
    bf16x8 r;
#pragma unroll
    for (int jj = 0; jj < 8; jj++) {
        float av = (float)a[jj], gv = (float)g[jj];
        r[jj] = (bf16_t)(av * fmaxf(gv, 0.0f));
    }
    *(bf16x8*)&act[i] = r;
}

// ---------------- fused flash attention, per (q-tile 64, b*h) ----------------
__global__ __launch_bounds__(256, 2)
void k_attn(const bf16_t* __restrict__ q, const bf16_t* __restrict__ k,
            const bf16_t* __restrict__ v, bf16_t* __restrict__ o) {
    __shared__ bf16_t q_lds[64][72];
    __shared__ bf16_t k_lds[64][72];
    __shared__ bf16_t vt_lds[64][72];
    __shared__ bf16_t p_lds[64][72];
    const int tid = threadIdx.x;
    const int lane = tid & 63;
    const int wave = tid >> 6;
    const int qt = blockIdx.x;   // 0..7
    const int bh = blockIdx.y;   // 0..255
    const bf16_t* qb = q + ((size_t)bh * 512 + qt * 64) * 64;
    const bf16_t* kb = k + (size_t)bh * 512 * 64;
    const bf16_t* vb = v + (size_t)bh * 512 * 64;
    const int sr = tid >> 2;          // 0..63
    const int sc = (tid & 3) * 16;    // 0,16,32,48
    { // stage Q once, folding in SCALE=0.125 (exact in bf16)
        bf16x8 a0 = *(const bf16x8*)(qb + sr * 64 + sc);
        bf16x8 a1 = *(const bf16x8*)(qb + sr * 64 + sc + 8);
        bf16x8 ra, rb;
#pragma unroll
        for (int j = 0; j < 8; j++) {
            ra[j] = (bf16_t)((float)a0[j] * 0.125f);
            rb[j] = (bf16_t)((float)a1[j] * 0.125f);
        }
        *(bf16x8*)&q_lds[sr][sc] = ra;
        *(bf16x8*)&q_lds[sr][sc + 8] = rb;
    }
    float mrow[4], lrow[4];
    f32x4 oacc[4] = {};
#pragma unroll
    for (int r = 0; r < 4; r++) { mrow[r] = -1e30f; lrow[r] = 0.f; }
    for (int kt = 0; kt < 8; kt++) {
        __syncthreads();
        {
            const bf16_t* ks = kb + ((size_t)kt * 64 + sr) * 64 + sc;
            const bf16_t* vs = vb + ((size_t)kt * 64 + sr) * 64 + sc;
            *(bf16x8*)&k_lds[sr][sc] = *(const bf16x8*)ks;
            *(bf16x8*)&k_lds[sr][sc + 8] = *(const bf16x8*)(ks + 8);
            bf16x8 v0 = *(const bf16x8*)vs;
            bf16x8 v1 = *(const bf16x8*)(vs + 8);
#pragma unroll
            for (int j = 0; j < 8; j++) {
                vt_lds[sc + j][sr] = v0[j];
                vt_lds[sc + 8 + j][sr] = v1[j];
            }
        }
        __syncthreads();
        f32x4 sacc[4] = {};
#pragma unroll
        for (int kk = 0; kk < 2; kk++) {
            bf16x8 aq = *(const bf16x8*)&q_lds[wave * 16 + (lane & 15)][kk * 32 + (lane >> 4) * 8];
#pragma unroll
            for (int c = 0; c < 4; c++) {
                bf16x8 bk8 = *(const bf16x8*)&k_lds[c * 16 + (lane & 15)][kk * 32 + (lane >> 4) * 8];
                sacc[c] = __builtin_amdgcn_mfma_f32_16x16x32_bf16(aq, bk8, sacc[c], 0, 0, 0);
            }
        }
#pragma unroll
        for (int r = 0; r < 4; r++) {
            float mx = fmaxf(fmaxf(sacc[0][r], sacc[1][r]), fmaxf(sacc[2][r], sacc[3][r]));
#pragma unroll
            for (int m = 1; m < 16; m <<= 1) mx = fmaxf(mx, __shfl_xor(mx, m, 64));
            float newm = fmaxf(mrow[r], mx);
            float fsc = __expf(mrow[r] - newm);
            mrow[r] = newm;
            float p0 = __expf(sacc[0][r] - newm);
            float p1 = __expf(sacc[1][r] - newm);
            float p2 = __expf(sacc[2][r] - newm);
            float p3 = __expf(sacc[3][r] - newm);
            float ps = p0 + p1 + p2 + p3;
#pragma unroll
            for (int m = 1; m < 16; m <<= 1) ps += __shfl_xor(ps, m, 64);
            lrow[r] = lrow[r] * fsc + ps;
#pragma unroll
            for (int c = 0; c < 4; c++) oacc[c][r] *= fsc;
            int qrow = wave * 16 + (lane >> 4) * 4 + r;
            p_lds[qrow][(lane & 15)] = (bf16_t)p0;
            p_lds[qrow][16 + (lane & 15)] = (bf16_t)p1;
            p_lds[qrow][32 + (lane & 15)] = (bf16_t)p2;
            p_lds[qrow][48 + (lane & 15)] = (bf16_t)p3;
        }
        __syncthreads();
#pragma unroll
        for (int kk = 0; kk < 2; kk++) {
            bf16x8 ap = *(const bf16x8*)&p_lds[wave * 16 + (lane & 15)][kk * 32 + (lane >> 4) * 8];
#pragma unroll
            for (int c = 0; c < 4; c++) {
                bf16x8 bv8 = *(const bf16x8*)&vt_lds[c * 16 + (lane & 15)][kk * 32 + (lane >> 4) * 8];
                oacc[c] = __builtin_amdgcn_mfma_f32_16x16x32_bf16(ap, bv8, oacc[c], 0, 0, 0);
            }
        }
    }
    const int b = bh >> 3, h = bh & 7;
#pragma unroll
    for (int r = 0; r < 4; r++) {
        int s = qt * 64 + wave * 16 + (lane >> 4) * 4 + r;
        float inv = 1.0f / lrow[r];
#pragma unroll
        for (int c = 0; c < 4; c++) {
            o[((size_t)b * 512 + s) * 512 + h * 64 + c * 16 + (lane & 15)] = (bf16_t)(oacc[c][r] * inv);
        }
    }
}

// =====================================================================================
extern "C" void kernel_launch(void* const* d_in, const int* in_sizes, int n_in,
                              void* d_out, int out_size, void* d_ws, size_t ws_size,
                              hipStream_t stream) {
    const float* x_in   = (const float*)d_in[0];
    const float* time_in= (const float*)d_in[1];
    const float* tw1    = (const float*)d_in[2];
    const float* tb1    = (const float*)d_in[3];
    const float* tw2    = (const float*)d_in[4];
    const float* tb2    = (const float*)d_in[5];
    const float* Wq     = (const float*)d_in[6];
    const float* bq     = (const float*)d_in[7];
    const float* Wk     = (const float*)d_in[8];
    const float* bk     = (const float*)d_in[9];
    const float* Wv     = (const float*)d_in[10];
    const float* bv     = (const float*)d_in[11];
    const float* Wo     = (const float*)d_in[12];
    const float* bo     = (const float*)d_in[13];
    const float* attn_g = (const float*)d_in[14];
    const float* attn_b = (const float*)d_in[15];
    const float* ffn_g  = (const float*)d_in[16];
    const float* ffn_b  = (const float*)d_in[17];
    const float* W1     = (const float*)d_in[18];
    const float* b1     = (const float*)d_in[19];
    const float* W2     = (const float*)d_in[20];
    const float* b2     = (const float*)d_in[21];
    const float* Wt     = (const float*)d_in[22];
    const float* bt     = (const float*)d_in[23];
    const float* head_g = (const float*)d_in[24];
    const float* head_b = (const float*)d_in[25];
    const float* Wh     = (const float*)d_in[26];
    const float* bh     = (const float*)d_in[27];

    size_t off = 0;
    auto alloc = [&](size_t bytes) {
        void* r = (char*)d_ws + off;
        off += (bytes + 255) & ~(size_t)255;
        return r;
    };
    bf16_t* wq_b  = (bf16_t*)alloc((size_t)4 * 512 * 512 * 2);
    bf16_t* wk_b  = (bf16_t*)alloc((size_t)4 * 512 * 512 * 2);
    bf16_t* wv_b  = (bf16_t*)alloc((size_t)4 * 512 * 512 * 2);
    bf16_t* wo_b  = (bf16_t*)alloc((size_t)4 * 512 * 512 * 2);
    bf16_t* w1_b  = (bf16_t*)alloc((size_t)4 * 2048 * 512 * 2);
    bf16_t* w2_b  = (bf16_t*)alloc((size_t)4 * 512 * 1024 * 2);
    float*  x_ws  = (float*)alloc((size_t)16384 * 512 * 4);
    bf16_t* h_b   = (bf16_t*)alloc((size_t)16384 * 512 * 2);
    bf16_t* q_b   = (bf16_t*)alloc((size_t)16384 * 512 * 2);
    bf16_t* k_b   = (bf16_t*)alloc((size_t)16384 * 512 * 2);
    bf16_t* v_b   = (bf16_t*)alloc((size_t)16384 * 512 * 2);
    bf16_t* o_b   = (bf16_t*)alloc((size_t)16384 * 512 * 2);
    bf16_t* h1_b  = (bf16_t*)alloc((size_t)16384 * 2048 * 2);
    bf16_t* act_b = (bf16_t*)alloc((size_t)16384 * 1024 * 2);
    float*  temb0 = (float*)alloc((size_t)32 * 512 * 4);
    float*  t1    = (float*)alloc((size_t)32 * 2048 * 4);
    float*  t2s   = (float*)alloc((size_t)32 * 2048 * 4);
    float*  tm_all= (float*)alloc((size_t)32 * 16384 * 4);
    float*  z     = (float*)alloc((size_t)32 * 512 * 4);

    // weight conversion (every call; deterministic)
    k_f2b<<<512, 256, 0, stream>>>(Wq, wq_b, 131072);
    k_f2b<<<512, 256, 0, stream>>>(Wk, wk_b, 131072);
    k_f2b<<<512, 256, 0, stream>>>(Wv, wv_b, 131072);
    k_f2b<<<512, 256, 0, stream>>>(Wo, wo_b, 131072);
    k_f2b<<<2048, 256, 0, stream>>>(W1, w1_b, 524288);
    k_f2b<<<1024, 256, 0, stream>>>(W2, w2_b, 262144);

    hipMemcpyAsync(x_ws, x_in, (size_t)16384 * 512 * 4, hipMemcpyDeviceToDevice, stream);

    // time pipeline (fp32, tiny)
    k_time_embed<<<32, 256, 0, stream>>>(time_in, temb0);
    k_gemm32<1><<<64, 256, 0, stream>>>(temb0, tw1, tb1, t1, 2048, 512);
    k_gemm32<2><<<64, 256, 0, stream>>>(t1, tw2, tb2, t2s, 2048, 2048);
    k_gemm32<0><<<512, 256, 0, stream>>>(t2s, Wt, bt, tm_all, 16384, 2048);

    for (int l = 0; l < 4; l++) {
        if (l == 0)
            k_ln<false><<<4096, 256, 0, stream>>>(x_ws, nullptr, nullptr, h_b);
        else
            k_ln<true><<<4096, 256, 0, stream>>>(x_ws, attn_g + l * 512, attn_b + l * 512, h_b);

        k_gemm_bt<EPI_QKV><<<dim3(128, 4), 256, 0, stream>>>(
            h_b, wq_b + (size_t)l * 262144, bq + l * 512, q_b, nullptr, 0, 16384, 512, 512);
        k_gemm_bt<EPI_QKV><<<dim3(128, 4), 256, 0, stream>>>(
            h_b, wk_b + (size_t)l * 262144, bk + l * 512, k_b, nullptr, 0, 16384, 512, 512);
        k_gemm_bt<EPI_QKV><<<dim3(128, 4), 256, 0, stream>>>(
            h_b, wv_b + (size_t)l * 262144, bv + l * 512, v_b, nullptr, 0, 16384, 512, 512);

        k_attn<<<dim3(8, 256), 256, 0, stream>>>(q_b, k_b, v_b, o_b);

        k_gemm_bt<EPI_RESID><<<dim3(128, 4), 256, 0, stream>>>(
            o_b, wo_b + (size_t)l * 262144, bo + l * 512, x_ws, nullptr, 0, 16384, 512, 512);

        k_ln<true><<<4096, 256, 0, stream>>>(x_ws, ffn_g + l * 512, ffn_b + l * 512, h_b);

        k_gemm_bt<EPI_FILM><<<dim3(128, 16), 256, 0, stream>>>(
            h_b, w1_b + (size_t)l * 1048576, b1 + l * 2048, h1_b, tm_all, l * 4096, 16384, 2048, 512);

        k_reglu<<<8192, 256, 0, stream>>>(h1_b, act_b);

        k_gemm_bt<EPI_RESID><<<dim3(128, 4), 256, 0, stream>>>(
            act_b, w2_b + (size_t)l * 524288, b2 + l * 512, x_ws, nullptr, 0, 16384, 512, 1024);
    }

    k_head_prep<<<8, 256, 0, stream>>>(x_ws, head_g, head_b, z);
    k_gemm32<0><<<16, 256, 0, stream>>>(z, Wh, bh, (float*)d_out, 512, 512);
}

// Round 2
// 1140.082 us; speedup vs baseline: 2.3112x; 2.3112x over previous
//
#include <hip/hip_runtime.h>
#include <math.h>

typedef __bf16 bf16_t;
typedef __bf16 bf16x8 __attribute__((ext_vector_type(8)));
typedef float f32x4 __attribute__((ext_vector_type(4)));

__device__ __forceinline__ void gload_lds16(const void* g, void* l) {
    __builtin_amdgcn_global_load_lds(
        (const __attribute__((address_space(1))) void*)g,
        (__attribute__((address_space(3))) void*)l, 16, 0, 0);
}

// ---------------- f32 -> bf16 convert ----------------
__global__ void k_f2b(const float* __restrict__ in, bf16_t* __restrict__ out, int n8) {
    int idx = blockIdx.x * 256 + threadIdx.x;
    if (idx >= n8) return;
    const float* p = in + (size_t)idx * 8;
    bf16x8 r;
#pragma unroll
    for (int j = 0; j < 8; j++) r[j] = (bf16_t)p[j];
    *(bf16x8*)(out + (size_t)idx * 8) = r;
}

// ---------------- sinusoidal time embedding ----------------
__global__ void k_time_embed(const float* __restrict__ time, float* __restrict__ temb0) {
    int b = blockIdx.x;
    int j = threadIdx.x;              // 0..255
    float f = __expf((float)j * -0.036118981458730134f); // -ln(10000)/255
    float e = time[b] * f;
    temb0[(size_t)b * 512 + j] = sinf(e);
    temb0[(size_t)b * 512 + 256 + j] = cosf(e);
}

// ---------------- LayerNorm (or plain cast) -> bf16, rows of 512 ----------------
template<bool DO_NORM>
__global__ void k_ln(const float* __restrict__ x, const float* __restrict__ g,
                     const float* __restrict__ b, bf16_t* __restrict__ out) {
    int row = blockIdx.x * 4 + (threadIdx.x >> 6);
    int lane = threadIdx.x & 63;
    const float* xr = x + (size_t)row * 512 + lane * 8;
    float4 v0 = *(const float4*)xr;
    float4 v1 = *(const float4*)(xr + 4);
    float vals[8] = {v0.x, v0.y, v0.z, v0.w, v1.x, v1.y, v1.z, v1.w};
    bf16x8 r;
    if (DO_NORM) {
        float s = 0.f, sq = 0.f;
#pragma unroll
        for (int j = 0; j < 8; j++) { s += vals[j]; sq += vals[j] * vals[j]; }
#pragma unroll
        for (int m = 1; m < 64; m <<= 1) { s += __shfl_xor(s, m, 64); sq += __shfl_xor(sq, m, 64); }
        float mean = s * (1.0f / 512.0f);
        float var = sq * (1.0f / 512.0f) - mean * mean;
        float rstd = rsqrtf(var + 1e-5f);
        float4 g0 = *(const float4*)(g + lane * 8);
        float4 g1 = *(const float4*)(g + lane * 8 + 4);
        float4 b0 = *(const float4*)(b + lane * 8);
        float4 b1 = *(const float4*)(b + lane * 8 + 4);
        float gs[8] = {g0.x, g0.y, g0.z, g0.w, g1.x, g1.y, g1.z, g1.w};
        float bs[8] = {b0.x, b0.y, b0.z, b0.w, b1.x, b1.y, b1.z, b1.w};
#pragma unroll
        for (int j = 0; j < 8; j++) r[j] = (bf16_t)((vals[j] - mean) * rstd * gs[j] + bs[j]);
    } else {
#pragma unroll
        for (int j = 0; j < 8; j++) r[j] = (bf16_t)vals[j];
    }
    *(bf16x8*)(out + (size_t)row * 512 + lane * 8) = r;
}

// ---------------- head prep: LN(x[:, -1]) -> relu -> f32 z[32,512] ----------------
__global__ void k_head_prep(const float* __restrict__ x, const float* __restrict__ g,
                            const float* __restrict__ b, float* __restrict__ z) {
    int row = blockIdx.x * 4 + (threadIdx.x >> 6); // 0..31
    int lane = threadIdx.x & 63;
    const float* xr = x + ((size_t)row * 512 + 511) * 512 + lane * 8;
    float4 v0 = *(const float4*)xr;
    float4 v1 = *(const float4*)(xr + 4);
    float vals[8] = {v0.x, v0.y, v0.z, v0.w, v1.x, v1.y, v1.z, v1.w};
    float s = 0.f, sq = 0.f;
#pragma unroll
    for (int j = 0; j < 8; j++) { s += vals[j]; sq += vals[j] * vals[j]; }
#pragma unroll
    for (int m = 1; m < 64; m <<= 1) { s += __shfl_xor(s, m, 64); sq += __shfl_xor(sq, m, 64); }
    float mean = s * (1.0f / 512.0f);
    float var = sq * (1.0f / 512.0f) - mean * mean;
    float rstd = rsqrtf(var + 1e-5f);
    float o[8];
#pragma unroll
    for (int j = 0; j < 8; j++) {
        float gv = g[lane * 8 + j], bv = b[lane * 8 + j];
        o[j] = fmaxf((vals[j] - mean) * rstd * gv + bv, 0.0f);
    }
    float* zr = z + (size_t)row * 512 + lane * 8;
    *(float4*)zr = make_float4(o[0], o[1], o[2], o[3]);
    *(float4*)(zr + 4) = make_float4(o[4], o[5], o[6], o[7]);
}

// ---------------- small fp32 GEMM: C[32,N] = act(A[32,K] @ W[N,K]^T + bias) ----------------
template<int ACT>  // 0 none, 1 gelu(exact), 2 silu
__global__ __launch_bounds__(256)
void k_gemm32(const float* __restrict__ A, const float* __restrict__ W,
              const float* __restrict__ bias, float* __restrict__ out,
              int N, int K) {
    __shared__ float Asm[32 * 516];
    int tid = threadIdx.x;
    int n0 = blockIdx.x * 32;
    int nl = tid >> 3;   // 0..31
    int bq = tid & 7;    // b = bq + 8j
    float acc[4] = {0.f, 0.f, 0.f, 0.f};
    for (int k0 = 0; k0 < K; k0 += 512) {
        __syncthreads();
#pragma unroll
        for (int i = 0; i < 16; i++) {
            int fi = tid + i * 256;      // float4 id in [0,4096)
            int row = fi >> 7;
            int cc = (fi & 127) << 2;
            *(float4*)&Asm[row * 516 + cc] = *(const float4*)&A[(size_t)row * K + k0 + cc];
        }
        __syncthreads();
        const float* Wr = W + (size_t)(n0 + nl) * K + k0;
        for (int kk = 0; kk < 512; kk += 4) {
            float4 w4 = *(const float4*)(Wr + kk);
#pragma unroll
            for (int j = 0; j < 4; j++) {
                float4 a4 = *(const float4*)&Asm[(bq + j * 8) * 516 + kk];
                acc[j] += a4.x * w4.x + a4.y * w4.y + a4.z * w4.z + a4.w * w4.w;
            }
        }
    }
#pragma unroll
    for (int j = 0; j < 4; j++) {
        float v = acc[j] + bias[n0 + nl];
        if (ACT == 1) v = 0.5f * v * (1.0f + erff(v * 0.70710678118654752f));
        if (ACT == 2) v = v / (1.0f + __expf(-v));
        out[(size_t)(bq + j * 8) * N + n0 + nl] = v;
    }
}

// ---------------- MFMA GEMM via global_load_lds, fused epilogues ----------------
// C[M=16384, Ntile] = A[.,K]bf16 @ W'[.,K]^T bf16 (+bias) with:
//   EPI_QKV:     N=1536 (merged q,k,v), writes head-major bf16 to 3 outputs
//   EPI_RESID:   N=512, float residual +=
//   EPI_FILMGLU: W1 GEMM (virtual N=2048) with paired a/g column tiling;
//                epilogue does FiLM + a*relu(g), writes act[16384,1024] bf16
enum { EPI_QKV = 0, EPI_RESID = 1, EPI_FILMGLU = 2 };

template<int EPI, int K>
__global__ __launch_bounds__(256, 4)
void k_gemm_bt(const bf16_t* __restrict__ A, const bf16_t* __restrict__ W,
               const float* __restrict__ bias, const float* __restrict__ bias2,
               const float* __restrict__ bias3,
               void* __restrict__ out0, void* __restrict__ out1, void* __restrict__ out2,
               const float* __restrict__ tm) {
    __shared__ __align__(16) bf16_t Abuf[128 * 64];
    __shared__ __align__(16) bf16_t Bbuf[128 * 64];
    const int tid = threadIdx.x;
    const int bx = blockIdx.x, by = blockIdx.y;
    const int m0 = bx * 128;
    const int lane = tid & 63;
    const int wave = tid >> 6;
    const int wr = (wave >> 1) * 64, wc = (wave & 1) * 64;

    // staging geometry: thread covers LDS bytes o = tid*16 + i*4096
    const int srow = tid >> 3;            // row base (0..31), +i*32
    const int goff = ((tid & 7) * 16) ^ ((srow & 7) << 4);  // pre-swizzled byte col
    const char* Ag = (const char*)A;
    const char* Wg = (const char*)W;
    char* AbL = (char*)Abuf + tid * 16;
    char* BbL = (char*)Bbuf + tid * 16;
    // B-row -> global W row mapping
    int growB[4];
#pragma unroll
    for (int i = 0; i < 4; i++) {
        int r = srow + i * 32;
        if (EPI == EPI_FILMGLU) {
            int half = (r >> 5) & 1;
            int base = by * 64 + (r >> 6) * 32 + (r & 31);
            growB[i] = half * 1024 + base;
        } else {
            growB[i] = by * 128 + r;
        }
    }

    f32x4 acc[4][4] = {};
    for (int k0 = 0; k0 < K * 2; k0 += 128) {   // k0 in bytes
        __syncthreads();
#pragma unroll
        for (int i = 0; i < 4; i++) {
            gload_lds16(Ag + (size_t)(m0 + srow + i * 32) * (K * 2) + k0 + goff, AbL + i * 4096);
            gload_lds16(Wg + (size_t)growB[i] * (K * 2) + k0 + goff, BbL + i * 4096);
        }
        __syncthreads();
#pragma unroll
        for (int kk = 0; kk < 2; kk++) {
            bf16x8 af[4], bfr[4];
#pragma unroll
            for (int i = 0; i < 4; i++) {
                int ar = wr + i * 16 + (lane & 15);
                af[i] = *(const bf16x8*)((const char*)Abuf + ar * 128 +
                         ((kk * 64 + (lane >> 4) * 16) ^ ((ar & 7) << 4)));
                int br = wc + i * 16 + (lane & 15);
                bfr[i] = *(const bf16x8*)((const char*)Bbuf + br * 128 +
                         ((kk * 64 + (lane >> 4) * 16) ^ ((br & 7) << 4)));
            }
#pragma unroll
            for (int i = 0; i < 4; i++)
#pragma unroll
                for (int j = 0; j < 4; j++)
                    acc[i][j] = __builtin_amdgcn_mfma_f32_16x16x32_bf16(af[i], bfr[j], acc[i][j], 0, 0, 0);
        }
    }

    const int b = m0 >> 9;   // uniform per block (128 rows within one batch)
    if (EPI == EPI_QKV) {
        const int which = by >> 2;
        bf16_t* op = (bf16_t*)(which == 0 ? out0 : which == 1 ? out1 : out2);
        const float* bp = which == 0 ? bias : which == 1 ? bias2 : bias3;
#pragma unroll
        for (int i = 0; i < 4; i++) {
#pragma unroll
            for (int r = 0; r < 4; r++) {
                int s = (m0 + wr + i * 16 + (lane >> 4) * 4 + r) & 511;
#pragma unroll
                for (int j = 0; j < 4; j++) {
                    int c = (by & 3) * 128 + wc + j * 16 + (lane & 15);
                    float v = acc[i][j][r] + bp[c];
                    int h = c >> 6, dh = c & 63;
                    op[(((size_t)b * 8 + h) * 512 + s) * 64 + dh] = (bf16_t)v;
                }
            }
        }
    } else if (EPI == EPI_RESID) {
        float* op = (float*)out0;
#pragma unroll
        for (int i = 0; i < 4; i++) {
#pragma unroll
            for (int r = 0; r < 4; r++) {
                int row = m0 + wr + i * 16 + (lane >> 4) * 4 + r;
#pragma unroll
                for (int j = 0; j < 4; j++) {
                    int col = by * 128 + wc + j * 16 + (lane & 15);
                    op[(size_t)row * 512 + col] += acc[i][j][r] + bias[col];
                }
            }
        }
    } else { // EPI_FILMGLU
        bf16_t* op = (bf16_t*)out0;
        const float* tml = tm + (size_t)b * 16384;
#pragma unroll
        for (int i = 0; i < 4; i++) {
#pragma unroll
            for (int r = 0; r < 4; r++) {
                int row = m0 + wr + i * 16 + (lane >> 4) * 4 + r;
#pragma unroll
                for (int jj = 0; jj < 2; jj++) {
                    int colA = by * 64 + (wave & 1) * 32 + jj * 16 + (lane & 15);
                    float av = acc[i][jj][r] + bias[colA];
                    float gv = acc[i][jj + 2][r] + bias[1024 + colA];
                    av = av * (1.0f + tml[colA]) + tml[2048 + colA];
                    gv = gv * (1.0f + tml[1024 + colA]) + tml[3072 + colA];
                    op[(size_t)row * 1024 + colA] = (bf16_t)(av * fmaxf(gv, 0.0f));
                }
            }
        }
    }
}

// ---------------- fused flash attention, per (q-tile 64, b*h) ----------------
__global__ __launch_bounds__(256, 2)
void k_attn(const bf16_t* __restrict__ q, const bf16_t* __restrict__ k,
            const bf16_t* __restrict__ v, bf16_t* __restrict__ o) {
    __shared__ bf16_t q_lds[64][72];
    __shared__ bf16_t k_lds[64][72];
    __shared__ bf16_t vt_lds[64][72];
    __shared__ bf16_t p_lds[64][72];
    const int tid = threadIdx.x;
    const int lane = tid & 63;
    const int wave = tid >> 6;
    const int qt = blockIdx.x;   // 0..7
    const int bh = blockIdx.y;   // 0..255
    const bf16_t* qb = q + ((size_t)bh * 512 + qt * 64) * 64;
    const bf16_t* kb = k + (size_t)bh * 512 * 64;
    const bf16_t* vb = v + (size_t)bh * 512 * 64;
    const int sr = tid >> 2;          // 0..63
    const int sc = (tid & 3) * 16;    // 0,16,32,48
    { // stage Q once, folding in SCALE=0.125 (exact in bf16)
        bf16x8 a0 = *(const bf16x8*)(qb + sr * 64 + sc);
        bf16x8 a1 = *(const bf16x8*)(qb + sr * 64 + sc + 8);
        bf16x8 ra, rb;
#pragma unroll
        for (int j = 0; j < 8; j++) {
            ra[j] = (bf16_t)((float)a0[j] * 0.125f);
            rb[j] = (bf16_t)((float)a1[j] * 0.125f);
        }
        *(bf16x8*)&q_lds[sr][sc] = ra;
        *(bf16x8*)&q_lds[sr][sc + 8] = rb;
    }
    float mrow[4], lrow[4];
    f32x4 oacc[4] = {};
#pragma unroll
    for (int r = 0; r < 4; r++) { mrow[r] = -1e30f; lrow[r] = 0.f; }
    for (int kt = 0; kt < 8; kt++) {
        __syncthreads();
        {
            const bf16_t* ks = kb + ((size_t)kt * 64 + sr) * 64 + sc;
            const bf16_t* vs = vb + ((size_t)kt * 64 + sr) * 64 + sc;
            *(bf16x8*)&k_lds[sr][sc] = *(const bf16x8*)ks;
            *(bf16x8*)&k_lds[sr][sc + 8] = *(const bf16x8*)(ks + 8);
            bf16x8 v0 = *(const bf16x8*)vs;
            bf16x8 v1 = *(const bf16x8*)(vs + 8);
#pragma unroll
            for (int j = 0; j < 8; j++) {
                vt_lds[sc + j][sr] = v0[j];
                vt_lds[sc + 8 + j][sr] = v1[j];
            }
        }
        __syncthreads();
        f32x4 sacc[4] = {};
#pragma unroll
        for (int kk = 0; kk < 2; kk++) {
            bf16x8 aq = *(const bf16x8*)&q_lds[wave * 16 + (lane & 15)][kk * 32 + (lane >> 4) * 8];
#pragma unroll
            for (int c = 0; c < 4; c++) {
                bf16x8 bk8 = *(const bf16x8*)&k_lds[c * 16 + (lane & 15)][kk * 32 + (lane >> 4) * 8];
                sacc[c] = __builtin_amdgcn_mfma_f32_16x16x32_bf16(aq, bk8, sacc[c], 0, 0, 0);
            }
        }
#pragma unroll
        for (int r = 0; r < 4; r++) {
            float mx = fmaxf(fmaxf(sacc[0][r], sacc[1][r]), fmaxf(sacc[2][r], sacc[3][r]));
#pragma unroll
            for (int m = 1; m < 16; m <<= 1) mx = fmaxf(mx, __shfl_xor(mx, m, 64));
            float newm = fmaxf(mrow[r], mx);
            float fsc = __expf(mrow[r] - newm);
            mrow[r] = newm;
            float p0 = __expf(sacc[0][r] - newm);
            float p1 = __expf(sacc[1][r] - newm);
            float p2 = __expf(sacc[2][r] - newm);
            float p3 = __expf(sacc[3][r] - newm);
            float ps = p0 + p1 + p2 + p3;
#pragma unroll
            for (int m = 1; m < 16; m <<= 1) ps += __shfl_xor(ps, m, 64);
            lrow[r] = lrow[r] * fsc + ps;
#pragma unroll
            for (int c = 0; c < 4; c++) oacc[c][r] *= fsc;
            int qrow = wave * 16 + (lane >> 4) * 4 + r;
            p_lds[qrow][(lane & 15)] = (bf16_t)p0;
            p_lds[qrow][16 + (lane & 15)] = (bf16_t)p1;
            p_lds[qrow][32 + (lane & 15)] = (bf16_t)p2;
            p_lds[qrow][48 + (lane & 15)] = (bf16_t)p3;
        }
        __syncthreads();
#pragma unroll
        for (int kk = 0; kk < 2; kk++) {
            bf16x8 ap = *(const bf16x8*)&p_lds[wave * 16 + (lane & 15)][kk * 32 + (lane >> 4) * 8];
#pragma unroll
            for (int c = 0; c < 4; c++) {
                bf16x8 bv8 = *(const bf16x8*)&vt_lds[c * 16 + (lane & 15)][kk * 32 + (lane >> 4) * 8];
                oacc[c] = __builtin_amdgcn_mfma_f32_16x16x32_bf16(ap, bv8, oacc[c], 0, 0, 0);
            }
        }
    }
    const int b = bh >> 3, h = bh & 7;
#pragma unroll
    for (int r = 0; r < 4; r++) {
        int s = qt * 64 + wave * 16 + (lane >> 4) * 4 + r;
        float inv = 1.0f / lrow[r];
#pragma unroll
        for (int c = 0; c < 4; c++) {
            o[((size_t)b * 512 + s) * 512 + h * 64 + c * 16 + (lane & 15)] = (bf16_t)(oacc[c][r] * inv);
        }
    }
}

// =====================================================================================
extern "C" void kernel_launch(void* const* d_in, const int* in_sizes, int n_in,
                              void* d_out, int out_size, void* d_ws, size_t ws_size,
                              hipStream_t stream) {
    const float* x_in   = (const float*)d_in[0];
    const float* time_in= (const float*)d_in[1];
    const float* tw1    = (const float*)d_in[2];
    const float* tb1    = (const float*)d_in[3];
    const float* tw2    = (const float*)d_in[4];
    const float* tb2    = (const float*)d_in[5];
    const float* Wq     = (const float*)d_in[6];
    const float* bq     = (const float*)d_in[7];
    const float* Wk     = (const float*)d_in[8];
    const float* bk     = (const float*)d_in[9];
    const float* Wv     = (const float*)d_in[10];
    const float* bv     = (const float*)d_in[11];
    const float* Wo     = (const float*)d_in[12];
    const float* bo     = (const float*)d_in[13];
    const float* attn_g = (const float*)d_in[14];
    const float* attn_b = (const float*)d_in[15];
    const float* ffn_g  = (const float*)d_in[16];
    const float* ffn_b  = (const float*)d_in[17];
    const float* W1     = (const float*)d_in[18];
    const float* b1     = (const float*)d_in[19];
    const float* W2     = (const float*)d_in[20];
    const float* b2     = (const float*)d_in[21];
    const float* Wt     = (const float*)d_in[22];
    const float* bt     = (const float*)d_in[23];
    const float* head_g = (const float*)d_in[24];
    const float* head_b = (const float*)d_in[25];
    const float* Wh     = (const float*)d_in[26];
    const float* bh     = (const float*)d_in[27];

    size_t off = 0;
    auto alloc = [&](size_t bytes) {
        void* r = (char*)d_ws + off;
        off += (bytes + 255) & ~(size_t)255;
        return r;
    };
    bf16_t* wqkv_b = (bf16_t*)alloc((size_t)4 * 3 * 512 * 512 * 2);  // [L][3][512][512]
    bf16_t* wo_b   = (bf16_t*)alloc((size_t)4 * 512 * 512 * 2);
    bf16_t* w1_b   = (bf16_t*)alloc((size_t)4 * 2048 * 512 * 2);
    bf16_t* w2_b   = (bf16_t*)alloc((size_t)4 * 512 * 1024 * 2);
    float*  x_ws   = (float*)alloc((size_t)16384 * 512 * 4);
    bf16_t* h_b    = (bf16_t*)alloc((size_t)16384 * 512 * 2);
    bf16_t* q_b    = (bf16_t*)alloc((size_t)16384 * 512 * 2);
    bf16_t* k_b    = (bf16_t*)alloc((size_t)16384 * 512 * 2);
    bf16_t* v_b    = (bf16_t*)alloc((size_t)16384 * 512 * 2);
    bf16_t* o_b    = (bf16_t*)alloc((size_t)16384 * 512 * 2);
    bf16_t* act_b  = (bf16_t*)alloc((size_t)16384 * 1024 * 2);
    float*  temb0  = (float*)alloc((size_t)32 * 512 * 4);
    float*  t1     = (float*)alloc((size_t)32 * 2048 * 4);
    float*  t2s    = (float*)alloc((size_t)32 * 2048 * 4);
    float*  tm_all = (float*)alloc((size_t)32 * 16384 * 4);
    float*  z      = (float*)alloc((size_t)32 * 512 * 4);

    // weight conversion (every call; deterministic)
    for (int l = 0; l < 4; l++) {
        k_f2b<<<128, 256, 0, stream>>>(Wq + (size_t)l * 262144, wqkv_b + ((size_t)l * 3 + 0) * 262144, 32768);
        k_f2b<<<128, 256, 0, stream>>>(Wk + (size_t)l * 262144, wqkv_b + ((size_t)l * 3 + 1) * 262144, 32768);
        k_f2b<<<128, 256, 0, stream>>>(Wv + (size_t)l * 262144, wqkv_b + ((size_t)l * 3 + 2) * 262144, 32768);
    }
    k_f2b<<<512, 256, 0, stream>>>(Wo, wo_b, 131072);
    k_f2b<<<2048, 256, 0, stream>>>(W1, w1_b, 524288);
    k_f2b<<<1024, 256, 0, stream>>>(W2, w2_b, 262144);

    hipMemcpyAsync(x_ws, x_in, (size_t)16384 * 512 * 4, hipMemcpyDeviceToDevice, stream);

    // time pipeline (fp32, tiny)
    k_time_embed<<<32, 256, 0, stream>>>(time_in, temb0);
    k_gemm32<1><<<64, 256, 0, stream>>>(temb0, tw1, tb1, t1, 2048, 512);
    k_gemm32<2><<<64, 256, 0, stream>>>(t1, tw2, tb2, t2s, 2048, 2048);
    k_gemm32<0><<<512, 256, 0, stream>>>(t2s, Wt, bt, tm_all, 16384, 2048);

    for (int l = 0; l < 4; l++) {
        if (l == 0)
            k_ln<false><<<4096, 256, 0, stream>>>(x_ws, nullptr, nullptr, h_b);
        else
            k_ln<true><<<4096, 256, 0, stream>>>(x_ws, attn_g + l * 512, attn_b + l * 512, h_b);

        k_gemm_bt<EPI_QKV, 512><<<dim3(128, 12), 256, 0, stream>>>(
            h_b, wqkv_b + (size_t)l * 786432,
            bq + l * 512, bk + l * 512, bv + l * 512,
            q_b, k_b, v_b, nullptr);

        k_attn<<<dim3(8, 256), 256, 0, stream>>>(q_b, k_b, v_b, o_b);

        k_gemm_bt<EPI_RESID, 512><<<dim3(128, 4), 256, 0, stream>>>(
            o_b, wo_b + (size_t)l * 262144,
            bo + l * 512, nullptr, nullptr,
            x_ws, nullptr, nullptr, nullptr);

        k_ln<true><<<4096, 256, 0, stream>>>(x_ws, ffn_g + l * 512, ffn_b + l * 512, h_b);

        k_gemm_bt<EPI_FILMGLU, 512><<<dim3(128, 16), 256, 0, stream>>>(
            h_b, w1_b + (size_t)l * 1048576,
            b1 + l * 2048, nullptr, nullptr,
            act_b, nullptr, nullptr, tm_all + l * 4096);

        k_gemm_bt<EPI_RESID, 1024><<<dim3(128, 4), 256, 0, stream>>>(
            act_b, w2_b + (size_t)l * 524288,
            b2 + l * 512, nullptr, nullptr,
            x_ws, nullptr, nullptr, nullptr);
    }

    k_head_prep<<<8, 256, 0, stream>>>(x_ws, head_g, head_b, z);
    k_gemm32<0><<<16, 256, 0, stream>>>(z, Wh, bh, (float*)d_out, 512, 512);
}